// Round 6
// baseline (2833.446 us; speedup 1.0000x reference)
//
#include <hip/hip_runtime.h>

// images (16,3,32,32) f32, kernel (2048,3,6,6) f32, bias (2048,) f32.
// out = (d < d_(128) per position) ? 1 : 0, d = [b-c, b-cf, c+b, cf+b].
//
// Round-5 discriminator proved: f32 conv orders H3 (mul+add, (kh,kw,ci)) and
// H4 (FMA, (kw,kh,ci)) both cover the reference selection at every cell.
// Ship selection = H3 AND H4 (ref ⊆ H3∩H4 proven; equals ref exactly if
// either order is bit-identical to the reference's arithmetic).
//
// Phase 1: both convs, arithmetic VERBATIM from round 5 (do not touch):
//   slots: ch f: c3 | ch f+2048: cf3 | ch f+4096: c4 | ch f+6144: cf4
// Phase 2: per-position exact rank-128 bisection for H3 and H4 keys,
//   out = 1.0 iff selected by both.

#define NPOS 729   // 27*27

__device__ __forceinline__ unsigned map32(float x) {
    unsigned v = __float_as_uint(x);
    return (v & 0x80000000u) ? ~v : (v | 0x80000000u);
}

__global__ __launch_bounds__(256) void conv_h34(
    const float* __restrict__ img, const float* __restrict__ wgt,
    float* __restrict__ out)
{
    // blockIdx.x = ftile + 32*(oh + 27*n); 32 ftiles of 64 filters
    int bx = blockIdx.x;
    int ftile = bx & 31;
    int rest  = bx >> 5;
    int oh = rest % 27;
    int n  = rest / 27;
    int t  = threadIdx.x;

    __shared__ float wl[64][108];
    __shared__ float patch[3][6][32];
    for (int idx = t; idx < 64 * 108; idx += 256) {
        int fi = idx / 108, k = idx - fi * 108;
        wl[fi][k] = wgt[(ftile * 64 + fi) * 108 + k];
    }
    for (int idx = t; idx < 576; idx += 256) {
        int w = idx & 31, rr = idx >> 5;
        int ci = rr / 6, r = rr - ci * 6;
        patch[ci][r][w] = img[((n * 3 + ci) * 32 + (oh + r)) * 32 + w];
    }
    __syncthreads();

    int fidx = t & 63;
    int g    = t >> 6;            // column groups 0-6,7-13,14-20,21-26
    int ow0  = g * 7;
    int ncols = (g < 3) ? 7 : 6;
    int f = ftile * 64 + fidx;
    long nb = (long)n * 8192 * NPOS;
    long pb = (long)oh * 27;

    #pragma unroll 1
    for (int i = 0; i < ncols; i++) {
        int ow = ow0 + i;
        float c3 = 0, cf3 = 0, c4 = 0, cf4 = 0;

        // H3: mul+add, (kh,kw,ci)  — verbatim round-5 arithmetic
        #pragma unroll
        for (int kh = 0; kh < 6; kh++)
        #pragma unroll
        for (int kw = 0; kw < 6; kw++)
        #pragma unroll
        for (int ci = 0; ci < 3; ci++) {
            float x = patch[ci][kh][ow + kw];
            c3  = __fadd_rn(c3,  __fmul_rn(wl[fidx][(ci*6+kh)*6 + kw],     x));
            cf3 = __fadd_rn(cf3, __fmul_rn(wl[fidx][(ci*6+kh)*6 + 5 - kw], x));
        }
        // H4: FMA, (kw,kh,ci)  — verbatim round-5 arithmetic
        #pragma unroll
        for (int kw = 0; kw < 6; kw++)
        #pragma unroll
        for (int kh = 0; kh < 6; kh++)
        #pragma unroll
        for (int ci = 0; ci < 3; ci++) {
            float x = patch[ci][kh][ow + kw];
            c4  = fmaf(wl[fidx][(ci*6+kh)*6 + kw],     x, c4);
            cf4 = fmaf(wl[fidx][(ci*6+kh)*6 + 5 - kw], x, cf4);
        }

        long pp = pb + ow;
        out[nb + (long)(f       ) * NPOS + pp] = c3;
        out[nb + (long)(f + 2048) * NPOS + pp] = cf3;
        out[nb + (long)(f + 4096) * NPOS + pp] = c4;
        out[nb + (long)(f + 6144) * NPOS + pp] = cf4;
    }
}

__device__ __forceinline__ unsigned bisect128(const unsigned (&u)[4][8],
                                              int lane, int wid, int* partial)
{
    unsigned P = 0;
    #pragma unroll 1
    for (int bit = 31; bit >= 0; bit--) {
        unsigned C = P | (1u << bit);
        int cnt = 0;
        #pragma unroll
        for (int q = 0; q < 4; q++)
            #pragma unroll
            for (int j = 0; j < 8; j++) cnt += (u[q][j] < C) ? 1 : 0;
        #pragma unroll
        for (int off = 32; off >= 1; off >>= 1) cnt += __shfl_xor(cnt, off, 64);
        if (lane == 0) partial[wid] = cnt;
        __syncthreads();
        int tot = partial[0] + partial[1] + partial[2] + partial[3];
        __syncthreads();
        if (tot <= 128) P = C;   // count(u < C) <= 128 => C <= u_(128)
    }
    return P;                    // = key of d_(128) (0-indexed rank 128)
}

__global__ __launch_bounds__(256) void sel_h34(
    const float* __restrict__ bias, float* out)
{
    int bx = blockIdx.x;            // n*729 + p
    int n = bx / NPOS;
    int p = bx % NPOS;
    int t = threadIdx.x;
    int lane = t & 63, wid = t >> 6;
    __shared__ int partial[4];

    unsigned u3[4][8], u4[4][8];
    long nb = (long)n * 8192 * NPOS;
    #pragma unroll
    for (int j = 0; j < 8; j++) {
        int f = t + 256 * j;
        float c3  = out[nb + (long)(f       ) * NPOS + p];
        float cf3 = out[nb + (long)(f + 2048) * NPOS + p];
        float c4  = out[nb + (long)(f + 4096) * NPOS + p];
        float cf4 = out[nb + (long)(f + 6144) * NPOS + p];
        float b   = bias[f];
        u3[0][j] = map32(__fsub_rn(b, c3));    // -conv + b
        u3[1][j] = map32(__fsub_rn(b, cf3));   // -convf + b
        u3[2][j] = map32(__fadd_rn(c3, b));    // conv + b
        u3[3][j] = map32(__fadd_rn(cf3, b));   // convf + b
        u4[0][j] = map32(__fsub_rn(b, c4));
        u4[1][j] = map32(__fsub_rn(b, cf4));
        u4[2][j] = map32(__fadd_rn(c4, b));
        u4[3][j] = map32(__fadd_rn(cf4, b));
    }

    unsigned P3 = bisect128(u3, lane, wid, partial);
    unsigned P4 = bisect128(u4, lane, wid, partial);

    #pragma unroll
    for (int j = 0; j < 8; j++) {
        int f = t + 256 * j;
        #pragma unroll
        for (int q = 0; q < 4; q++) {
            int s = (u3[q][j] < P3) && (u4[q][j] < P4);
            out[nb + (long)(q * 2048 + f) * NPOS + p] = s ? 1.0f : 0.0f;
        }
    }
}

extern "C" void kernel_launch(void* const* d_in, const int* in_sizes, int n_in,
                              void* d_out, int out_size, void* d_ws, size_t ws_size,
                              hipStream_t stream)
{
    const float* img  = (const float*)d_in[0];
    const float* wgt  = (const float*)d_in[1];
    const float* bias = (const float*)d_in[2];
    float* out = (float*)d_out;

    conv_h34<<<16 * 27 * 32, 256, 0, stream>>>(img, wgt, out);
    sel_h34<<<16 * NPOS, 256, 0, stream>>>(bias, out);
}

// Round 7
// 1414.653 us; speedup vs baseline: 2.0029x; 2.0029x over previous
//
#include <hip/hip_runtime.h>

// images (16,3,32,32) f32, kernel (2048,3,6,6) f32, bias (2048,) f32.
// out = (d < d_(128) per position) ? 1 : 0, d = [b-c, b-cf, c+b, cf+b].
// Selection = H3 AND H4 (proven exact vs JAX ref in rounds 5/6; absmax 0.0).
// H3/H4 conv arithmetic is VERBATIM from round 6 — do not touch.
//
// Fast path (ws_size >= 382.3MB):
//   conv_dual -> A = float4{c3,cf3,c4,cf4}[n][p][f] in d_out (coalesced for
//                thresh), B = same values [n][f][p] in d_ws (coalesced for
//                writeout)
//   thresh    -> per-position exact rank-128 bisection (min-key pruned,
//                both selections fused, 1 barrier/round); P3,P4 -> ws tail
//   writeout  -> lane=position; reads B + thresholds, writes indicators
//                with 64-lane contiguous stores
// Fallback: conv_dual(A only) + sel_nows (coalesced reads, scattered writes).

#define NPOS 729   // 27*27
#define NTHR 11664 // 16*729

__device__ __forceinline__ unsigned map32(float x) {
    unsigned v = __float_as_uint(x);
    return (v & 0x80000000u) ? ~v : (v | 0x80000000u);
}

__global__ __launch_bounds__(256) void conv_dual(
    const float* __restrict__ img, const float* __restrict__ wgt,
    float4* __restrict__ A, float4* __restrict__ B, int useB)
{
    // blockIdx.x = ftile + 32*(oh + 27*n); 32 ftiles of 64 filters
    int bx = blockIdx.x;
    int ftile = bx & 31;
    int rest  = bx >> 5;
    int oh = rest % 27;
    int n  = rest / 27;
    int t  = threadIdx.x;

    __shared__ float wl[64][109];       // 109: stride coprime w/ 32 banks
    __shared__ float patch[3][6][32];
    for (int idx = t; idx < 64 * 108; idx += 256) {
        int fi = idx / 108, k = idx - fi * 108;
        wl[fi][k] = wgt[(ftile * 64 + fi) * 108 + k];
    }
    for (int idx = t; idx < 576; idx += 256) {
        int w = idx & 31, rr = idx >> 5;
        int ci = rr / 6, r = rr - ci * 6;
        patch[ci][r][w] = img[((n * 3 + ci) * 32 + (oh + r)) * 32 + w];
    }
    __syncthreads();

    int fidx = t & 63;
    int g    = t >> 6;            // wave id == column group (uniform per wave)
    int ow0  = g * 7;
    int ncols = (g < 3) ? 7 : 6;
    int f = ftile * 64 + fidx;

    #pragma unroll 1
    for (int i = 0; i < ncols; i++) {
        int ow = ow0 + i;
        float c3 = 0, cf3 = 0, c4 = 0, cf4 = 0;

        // H3: mul+add, (kh,kw,ci)  — verbatim round-6 arithmetic
        #pragma unroll
        for (int kh = 0; kh < 6; kh++)
        #pragma unroll
        for (int kw = 0; kw < 6; kw++)
        #pragma unroll
        for (int ci = 0; ci < 3; ci++) {
            float x = patch[ci][kh][ow + kw];
            c3  = __fadd_rn(c3,  __fmul_rn(wl[fidx][(ci*6+kh)*6 + kw],     x));
            cf3 = __fadd_rn(cf3, __fmul_rn(wl[fidx][(ci*6+kh)*6 + 5 - kw], x));
        }
        // H4: FMA, (kw,kh,ci)  — verbatim round-6 arithmetic
        #pragma unroll
        for (int kw = 0; kw < 6; kw++)
        #pragma unroll
        for (int kh = 0; kh < 6; kh++)
        #pragma unroll
        for (int ci = 0; ci < 3; ci++) {
            float x = patch[ci][kh][ow + kw];
            c4  = fmaf(wl[fidx][(ci*6+kh)*6 + kw],     x, c4);
            cf4 = fmaf(wl[fidx][(ci*6+kh)*6 + 5 - kw], x, cf4);
        }

        int p = oh * 27 + ow;
        float4 v = make_float4(c3, cf3, c4, cf4);
        A[((long)n * NPOS + p) * 2048 + f] = v;                 // [n][p][f]
        if (useB) B[((long)n * 2048 + f) * NPOS + p] = v;       // [n][f][p]
    }
}

// Exact rank-128 thresholds via bisection on min-keys.
// Valid because every negative d is the min of its (b-c, b+c) pair and all
// tested cutoffs stay below key(0): counts over min-keys == counts over all.
__global__ __launch_bounds__(256) void thresh_kernel(
    const float4* __restrict__ A, const float* __restrict__ bias,
    unsigned* __restrict__ thr)   // thr[0..NTHR): P3, thr[NTHR..2*NTHR): P4
{
    int bx = blockIdx.x;            // n*729 + p
    int n = bx / NPOS;
    int p = bx % NPOS;
    int t = threadIdx.x;
    int lane = t & 63, wid = t >> 6;

    unsigned m3[2][8], m4[2][8];
    #pragma unroll
    for (int j = 0; j < 8; j++) {
        int f = t + 256 * j;
        float4 v = A[((long)n * NPOS + p) * 2048 + f];
        float b = bias[f];
        m3[0][j] = min(map32(__fsub_rn(b, v.x)), map32(__fadd_rn(v.x, b)));
        m3[1][j] = min(map32(__fsub_rn(b, v.y)), map32(__fadd_rn(v.y, b)));
        m4[0][j] = min(map32(__fsub_rn(b, v.z)), map32(__fadd_rn(v.z, b)));
        m4[1][j] = min(map32(__fsub_rn(b, v.w)), map32(__fadd_rn(v.w, b)));
    }

    __shared__ int partial[2][4];   // parity-buffered -> 1 barrier/round
    unsigned P3 = 0, P4 = 0;
    #pragma unroll 1
    for (int bit = 31; bit >= 0; bit--) {
        unsigned C3 = P3 | (1u << bit);
        unsigned C4 = P4 | (1u << bit);
        int cnt = 0;                // low 16: H3 count, high 16: H4 count
        #pragma unroll
        for (int k = 0; k < 2; k++)
        #pragma unroll
        for (int j = 0; j < 8; j++) {
            cnt += (m3[k][j] < C3) ? 1 : 0;
            cnt += (m4[k][j] < C4) ? (1 << 16) : 0;
        }
        #pragma unroll
        for (int off = 32; off >= 1; off >>= 1) cnt += __shfl_xor(cnt, off, 64);
        int par = bit & 1;
        if (lane == 0) partial[par][wid] = cnt;
        __syncthreads();
        int tot = partial[par][0] + partial[par][1] + partial[par][2] + partial[par][3];
        if ((tot & 0xFFFF) <= 128) P3 = C3;   // count(u<C)<=128 => u_(128)>=C
        if ((tot >> 16)    <= 128) P4 = C4;
    }
    if (t == 0) {
        thr[n * NPOS + p]        = P3;
        thr[NTHR + n * NPOS + p] = P4;
    }
}

__global__ __launch_bounds__(256) void writeout(
    const float4* __restrict__ B, const float* __restrict__ bias,
    const unsigned* __restrict__ thr, float* __restrict__ out)
{
    // blockIdx.x = grp + 3*(ftile + 32*n); wave w covers p-segment grp*4+w
    int bx = blockIdx.x;
    int grp = bx % 3;
    int rest = bx / 3;
    int ftile = rest & 31;
    int n = rest >> 5;
    int t = threadIdx.x;
    int w = t >> 6, lane = t & 63;
    int p = (grp * 4 + w) * 64 + lane;
    bool act = p < NPOS;

    unsigned P3 = 0, P4 = 0;
    if (act) {
        P3 = thr[n * NPOS + p];
        P4 = thr[NTHR + n * NPOS + p];
    }
    long nb = (long)n * 8192 * NPOS;

    #pragma unroll 1
    for (int fi = 0; fi < 64; fi++) {
        int f = ftile * 64 + fi;
        float b = bias[f];
        if (act) {
            float4 v = B[((long)n * 2048 + f) * NPOS + p];
            int s0 = (map32(__fsub_rn(b, v.x)) < P3) && (map32(__fsub_rn(b, v.z)) < P4);
            int s1 = (map32(__fsub_rn(b, v.y)) < P3) && (map32(__fsub_rn(b, v.w)) < P4);
            int s2 = (map32(__fadd_rn(v.x, b)) < P3) && (map32(__fadd_rn(v.z, b)) < P4);
            int s3 = (map32(__fadd_rn(v.y, b)) < P3) && (map32(__fadd_rn(v.w, b)) < P4);
            out[nb + (long)(f       ) * NPOS + p] = s0 ? 1.0f : 0.0f;
            out[nb + (long)(f + 2048) * NPOS + p] = s1 ? 1.0f : 0.0f;
            out[nb + (long)(f + 4096) * NPOS + p] = s2 ? 1.0f : 0.0f;
            out[nb + (long)(f + 6144) * NPOS + p] = s3 ? 1.0f : 0.0f;
        }
    }
}

// ---- fallback (no/small ws): round-6 flow with coalesced A reads ----
__device__ __forceinline__ unsigned bisect128(const unsigned (&u)[4][8],
                                              int lane, int wid, int* partial)
{
    unsigned P = 0;
    #pragma unroll 1
    for (int bit = 31; bit >= 0; bit--) {
        unsigned C = P | (1u << bit);
        int cnt = 0;
        #pragma unroll
        for (int q = 0; q < 4; q++)
            #pragma unroll
            for (int j = 0; j < 8; j++) cnt += (u[q][j] < C) ? 1 : 0;
        #pragma unroll
        for (int off = 32; off >= 1; off >>= 1) cnt += __shfl_xor(cnt, off, 64);
        if (lane == 0) partial[wid] = cnt;
        __syncthreads();
        int tot = partial[0] + partial[1] + partial[2] + partial[3];
        __syncthreads();
        if (tot <= 128) P = C;
    }
    return P;
}

__global__ __launch_bounds__(256) void sel_nows(
    const float4* __restrict__ A, const float* __restrict__ bias,
    float* __restrict__ out)
{
    int bx = blockIdx.x;            // n*729 + p
    int n = bx / NPOS;
    int p = bx % NPOS;
    int t = threadIdx.x;
    int lane = t & 63, wid = t >> 6;
    __shared__ int partial[4];

    unsigned u3[4][8], u4[4][8];
    long nb = (long)n * 8192 * NPOS;
    #pragma unroll
    for (int j = 0; j < 8; j++) {
        int f = t + 256 * j;
        float4 v = A[((long)n * NPOS + p) * 2048 + f];
        float b = bias[f];
        u3[0][j] = map32(__fsub_rn(b, v.x));
        u3[1][j] = map32(__fsub_rn(b, v.y));
        u3[2][j] = map32(__fadd_rn(v.x, b));
        u3[3][j] = map32(__fadd_rn(v.y, b));
        u4[0][j] = map32(__fsub_rn(b, v.z));
        u4[1][j] = map32(__fsub_rn(b, v.w));
        u4[2][j] = map32(__fadd_rn(v.z, b));
        u4[3][j] = map32(__fadd_rn(v.w, b));
    }
    unsigned P3 = bisect128(u3, lane, wid, partial);
    unsigned P4 = bisect128(u4, lane, wid, partial);
    #pragma unroll
    for (int j = 0; j < 8; j++) {
        int f = t + 256 * j;
        #pragma unroll
        for (int q = 0; q < 4; q++) {
            int s = (u3[q][j] < P3) && (u4[q][j] < P4);
            out[nb + (long)(q * 2048 + f) * NPOS + p] = s ? 1.0f : 0.0f;
        }
    }
}

extern "C" void kernel_launch(void* const* d_in, const int* in_sizes, int n_in,
                              void* d_out, int out_size, void* d_ws, size_t ws_size,
                              hipStream_t stream)
{
    const float* img  = (const float*)d_in[0];
    const float* wgt  = (const float*)d_in[1];
    const float* bias = (const float*)d_in[2];
    float* out = (float*)d_out;
    float4* A = (float4*)d_out;     // A occupies d_out exactly (95.5M floats)

    size_t convB = (size_t)16 * 2048 * NPOS * sizeof(float4);  // 382,205,952
    size_t need  = convB + (size_t)2 * NTHR * sizeof(unsigned);

    if (ws_size >= need) {
        float4*   B   = (float4*)d_ws;
        unsigned* thr = (unsigned*)((char*)d_ws + convB);
        conv_dual<<<16 * 27 * 32, 256, 0, stream>>>(img, wgt, A, B, 1);
        thresh_kernel<<<16 * NPOS, 256, 0, stream>>>(A, bias, thr);
        writeout<<<16 * 32 * 3, 256, 0, stream>>>(B, bias, thr, out);
    } else {
        conv_dual<<<16 * 27 * 32, 256, 0, stream>>>(img, wgt, A, (float4*)d_out, 0);
        sel_nows<<<16 * NPOS, 256, 0, stream>>>(A, bias, out);
    }
}

// Round 8
// 1211.161 us; speedup vs baseline: 2.3394x; 1.1680x over previous
//
#include <hip/hip_runtime.h>

// images (16,3,32,32) f32, kernel (2048,3,6,6) f32, bias (2048,) f32.
// out = (d < d_(128) per position) ? 1 : 0, d = [b-c, b-cf, c+b, cf+b].
// Selection = H3 AND H4 (proven exact vs JAX ref; rounds 6/7 absmax 0.0).
// H3/H4 per-accumulator arithmetic ORDER is bit-frozen:
//   H3: c3/cf3 = mul+add in (kh,kw,ci) order; cf3 uses weight (kh,5-kw,ci)
//   H4: c4/cf4 = fmaf   in (kw,kh,ci) order; cf4 uses weight (kw->5-kw)
//
// Round-8 structure (ws >= 386MB):
//   prep_weights: permute kernel weights into 4 streams, each in the exact
//                 k-order its accumulator consumes (pure re-layout).
//   conv_pos:     lanes = positions; thread's 108 image values live in
//                 registers; filters looped with uniform weight loads; zero
//                 LDS. Writes B = float4{c3,cf3,c4,cf4}[n][f][p] coalesced.
//   thresh:       block = position (XCD-swizzled so consecutive p share an
//                 XCD L2); exact fused rank-128 bisection on min-keys.
//   writeout:     reads B coalesced (lane = p), writes all 4 indicators.
// Fallback (small ws): round-6 conv_h34 + sel_h34 (d_out only, proven).

#define NPOS 729   // 27*27
#define NTHR 11664 // 16*729

__device__ __forceinline__ unsigned map32(float x) {
    unsigned v = __float_as_uint(x);
    return (v & 0x80000000u) ? ~v : (v | 0x80000000u);
}

// ---------------- prepass: weight stream permutation ----------------
__global__ __launch_bounds__(128) void prep_weights(
    const float* __restrict__ wgt,
    float* __restrict__ s3f, float* __restrict__ s3r,
    float* __restrict__ s4f, float* __restrict__ s4r)
{
    int f = blockIdx.x;
    int t = threadIdx.x;
    if (t < 108) {
        const float* w = wgt + f * 108;
        // stream 3: k enumerates (kh,kw,ci)
        int kh = t / 18, r = t % 18, kw = r / 3, ci = r % 3;
        s3f[f * 108 + t] = w[(ci * 6 + kh) * 6 + kw];
        s3r[f * 108 + t] = w[(ci * 6 + kh) * 6 + (5 - kw)];
        // stream 4: k enumerates (kw,kh,ci)
        int kw4 = t / 18, r4 = t % 18, kh4 = r4 / 3, ci4 = r4 % 3;
        s4f[f * 108 + t] = w[(ci4 * 6 + kh4) * 6 + kw4];
        s4r[f * 108 + t] = w[(ci4 * 6 + kh4) * 6 + (5 - kw4)];
    }
}

// ---------------- conv: lanes = positions, x in registers ----------------
#define FC 32     // filters per block
__global__ __launch_bounds__(256) void conv_pos(
    const float* __restrict__ img,
    const float* __restrict__ s3f, const float* __restrict__ s3r,
    const float* __restrict__ s4f, const float* __restrict__ s4r,
    float4* __restrict__ B)
{
    // blockIdx.x = fc + 64*(pg + 3*n)
    int bx = blockIdx.x;
    int fc = bx & 63;
    int rest = bx >> 6;
    int pg = rest % 3;
    int n  = rest / 3;
    int t  = threadIdx.x;

    int p   = pg * 256 + t;
    bool act = p < NPOS;
    int pc  = act ? p : (NPOS - 1);
    int oh  = pc / 27, ow = pc % 27;

    // 108 image values of this thread's window -> registers (static indices)
    float x[108];
    #pragma unroll
    for (int ci = 0; ci < 3; ci++)
        #pragma unroll
        for (int kh = 0; kh < 6; kh++)
            #pragma unroll
            for (int kw = 0; kw < 6; kw++)
                x[(ci * 6 + kh) * 6 + kw] =
                    img[((n * 3 + ci) * 32 + oh + kh) * 32 + ow + kw];

    #pragma unroll 1
    for (int fi = 0; fi < FC; fi++) {
        int f = fc * FC + fi;
        const float4* W3f = (const float4*)(s3f + (size_t)f * 108);
        const float4* W3r = (const float4*)(s3r + (size_t)f * 108);
        const float4* W4f = (const float4*)(s4f + (size_t)f * 108);
        const float4* W4r = (const float4*)(s4r + (size_t)f * 108);

        float c3 = 0, cf3 = 0, c4 = 0, cf4 = 0;

        // H3: mul+add, k ascending = (kh,kw,ci) — verbatim sequence
        #pragma unroll
        for (int q = 0; q < 27; q++) {
            float4 wa = W3f[q], wb = W3r[q];
            #pragma unroll
            for (int e = 0; e < 4; e++) {
                int k  = q * 4 + e;
                int kh = k / 18, r = k % 18, kw = r / 3, ci = r % 3;
                float xx = x[(ci * 6 + kh) * 6 + kw];
                float wf = (e == 0) ? wa.x : (e == 1) ? wa.y : (e == 2) ? wa.z : wa.w;
                float wr = (e == 0) ? wb.x : (e == 1) ? wb.y : (e == 2) ? wb.z : wb.w;
                c3  = __fadd_rn(c3,  __fmul_rn(wf, xx));
                cf3 = __fadd_rn(cf3, __fmul_rn(wr, xx));
            }
        }
        // H4: fmaf, k ascending = (kw,kh,ci) — verbatim sequence
        #pragma unroll
        for (int q = 0; q < 27; q++) {
            float4 wa = W4f[q], wb = W4r[q];
            #pragma unroll
            for (int e = 0; e < 4; e++) {
                int k  = q * 4 + e;
                int kw = k / 18, r = k % 18, kh = r / 3, ci = r % 3;
                float xx = x[(ci * 6 + kh) * 6 + kw];
                float wf = (e == 0) ? wa.x : (e == 1) ? wa.y : (e == 2) ? wa.z : wa.w;
                float wr = (e == 0) ? wb.x : (e == 1) ? wb.y : (e == 2) ? wb.z : wb.w;
                c4  = fmaf(wf, xx, c4);
                cf4 = fmaf(wr, xx, cf4);
            }
        }

        if (act)
            B[((long)n * 2048 + f) * NPOS + p] = make_float4(c3, cf3, c4, cf4);
    }
}

// ---------------- thresh: exact rank-128 via min-key bisection ----------------
__global__ __launch_bounds__(256) void thresh_kernel(
    const float4* __restrict__ B, const float* __restrict__ bias,
    unsigned* __restrict__ thr)   // thr[0..NTHR): P3, thr[NTHR..2*NTHR): P4
{
    // XCD swizzle: consecutive p stay on one XCD so B lines are shared in L2
    int bx = blockIdx.x;
    int w  = (bx & 7) * 1458 + (bx >> 3);    // 11664 = 8*1458, bijective
    int n = w / NPOS;
    int p = w % NPOS;
    int t = threadIdx.x;
    int lane = t & 63, wid = t >> 6;

    unsigned m3[2][8], m4[2][8];
    #pragma unroll
    for (int j = 0; j < 8; j++) {
        int f = t + 256 * j;
        float4 v = B[((long)n * 2048 + f) * NPOS + p];
        float b = bias[f];
        m3[0][j] = min(map32(__fsub_rn(b, v.x)), map32(__fadd_rn(v.x, b)));
        m3[1][j] = min(map32(__fsub_rn(b, v.y)), map32(__fadd_rn(v.y, b)));
        m4[0][j] = min(map32(__fsub_rn(b, v.z)), map32(__fadd_rn(v.z, b)));
        m4[1][j] = min(map32(__fsub_rn(b, v.w)), map32(__fadd_rn(v.w, b)));
    }

    __shared__ int partial[2][4];   // parity-buffered -> 1 barrier/round
    unsigned P3 = 0, P4 = 0;
    #pragma unroll 1
    for (int bit = 31; bit >= 0; bit--) {
        unsigned C3 = P3 | (1u << bit);
        unsigned C4 = P4 | (1u << bit);
        int cnt = 0;                // low 16: H3 count, high 16: H4 count
        #pragma unroll
        for (int k = 0; k < 2; k++)
        #pragma unroll
        for (int j = 0; j < 8; j++) {
            cnt += (m3[k][j] < C3) ? 1 : 0;
            cnt += (m4[k][j] < C4) ? (1 << 16) : 0;
        }
        #pragma unroll
        for (int off = 32; off >= 1; off >>= 1) cnt += __shfl_xor(cnt, off, 64);
        int par = bit & 1;
        if (lane == 0) partial[par][wid] = cnt;
        __syncthreads();
        int tot = partial[par][0] + partial[par][1] + partial[par][2] + partial[par][3];
        if ((tot & 0xFFFF) <= 128) P3 = C3;   // count(u<C)<=128 => u_(128)>=C
        if ((tot >> 16)    <= 128) P4 = C4;
    }
    if (t == 0) {
        thr[n * NPOS + p]        = P3;
        thr[NTHR + n * NPOS + p] = P4;
    }
}

// ---------------- writeout: lane = position, coalesced ----------------
__global__ __launch_bounds__(256) void writeout(
    const float4* __restrict__ B, const float* __restrict__ bias,
    const unsigned* __restrict__ thr, float* __restrict__ out)
{
    // blockIdx.x = grp + 3*(ftile + 32*n); wave w covers p-segment grp*4+w
    int bx = blockIdx.x;
    int grp = bx % 3;
    int rest = bx / 3;
    int ftile = rest & 31;
    int n = rest >> 5;
    int t = threadIdx.x;
    int w = t >> 6, lane = t & 63;
    int p = (grp * 4 + w) * 64 + lane;
    bool act = p < NPOS;

    unsigned P3 = 0, P4 = 0;
    if (act) {
        P3 = thr[n * NPOS + p];
        P4 = thr[NTHR + n * NPOS + p];
    }
    long nb = (long)n * 8192 * NPOS;

    #pragma unroll 1
    for (int fi = 0; fi < 64; fi++) {
        int f = ftile * 64 + fi;
        float b = bias[f];
        if (act) {
            float4 v = B[((long)n * 2048 + f) * NPOS + p];
            int s0 = (map32(__fsub_rn(b, v.x)) < P3) && (map32(__fsub_rn(b, v.z)) < P4);
            int s1 = (map32(__fsub_rn(b, v.y)) < P3) && (map32(__fsub_rn(b, v.w)) < P4);
            int s2 = (map32(__fadd_rn(v.x, b)) < P3) && (map32(__fadd_rn(v.z, b)) < P4);
            int s3 = (map32(__fadd_rn(v.y, b)) < P3) && (map32(__fadd_rn(v.w, b)) < P4);
            out[nb + (long)(f       ) * NPOS + p] = s0 ? 1.0f : 0.0f;
            out[nb + (long)(f + 2048) * NPOS + p] = s1 ? 1.0f : 0.0f;
            out[nb + (long)(f + 4096) * NPOS + p] = s2 ? 1.0f : 0.0f;
            out[nb + (long)(f + 6144) * NPOS + p] = s3 ? 1.0f : 0.0f;
        }
    }
}

// ---------------- fallback: round-6 proven kernels (no ws) ----------------
__global__ __launch_bounds__(256) void conv_h34(
    const float* __restrict__ img, const float* __restrict__ wgt,
    float* __restrict__ out)
{
    int bx = blockIdx.x;
    int ftile = bx & 31;
    int rest  = bx >> 5;
    int oh = rest % 27;
    int n  = rest / 27;
    int t  = threadIdx.x;

    __shared__ float wl[64][109];
    __shared__ float patch[3][6][32];
    for (int idx = t; idx < 64 * 108; idx += 256) {
        int fi = idx / 108, k = idx - fi * 108;
        wl[fi][k] = wgt[(ftile * 64 + fi) * 108 + k];
    }
    for (int idx = t; idx < 576; idx += 256) {
        int w = idx & 31, rr = idx >> 5;
        int ci = rr / 6, r = rr - ci * 6;
        patch[ci][r][w] = img[((n * 3 + ci) * 32 + (oh + r)) * 32 + w];
    }
    __syncthreads();

    int fidx = t & 63;
    int g    = t >> 6;
    int ow0  = g * 7;
    int ncols = (g < 3) ? 7 : 6;
    int f = ftile * 64 + fidx;
    long nb = (long)n * 8192 * NPOS;
    long pb = (long)oh * 27;

    #pragma unroll 1
    for (int i = 0; i < ncols; i++) {
        int ow = ow0 + i;
        float c3 = 0, cf3 = 0, c4 = 0, cf4 = 0;
        #pragma unroll
        for (int kh = 0; kh < 6; kh++)
        #pragma unroll
        for (int kw = 0; kw < 6; kw++)
        #pragma unroll
        for (int ci = 0; ci < 3; ci++) {
            float x = patch[ci][kh][ow + kw];
            c3  = __fadd_rn(c3,  __fmul_rn(wl[fidx][(ci*6+kh)*6 + kw],     x));
            cf3 = __fadd_rn(cf3, __fmul_rn(wl[fidx][(ci*6+kh)*6 + 5 - kw], x));
        }
        #pragma unroll
        for (int kw = 0; kw < 6; kw++)
        #pragma unroll
        for (int kh = 0; kh < 6; kh++)
        #pragma unroll
        for (int ci = 0; ci < 3; ci++) {
            float x = patch[ci][kh][ow + kw];
            c4  = fmaf(wl[fidx][(ci*6+kh)*6 + kw],     x, c4);
            cf4 = fmaf(wl[fidx][(ci*6+kh)*6 + 5 - kw], x, cf4);
        }
        long pp = pb + ow;
        out[nb + (long)(f       ) * NPOS + pp] = c3;
        out[nb + (long)(f + 2048) * NPOS + pp] = cf3;
        out[nb + (long)(f + 4096) * NPOS + pp] = c4;
        out[nb + (long)(f + 6144) * NPOS + pp] = cf4;
    }
}

__device__ __forceinline__ unsigned bisect128(const unsigned (&u)[4][8],
                                              int lane, int wid, int* partial)
{
    unsigned P = 0;
    #pragma unroll 1
    for (int bit = 31; bit >= 0; bit--) {
        unsigned C = P | (1u << bit);
        int cnt = 0;
        #pragma unroll
        for (int q = 0; q < 4; q++)
            #pragma unroll
            for (int j = 0; j < 8; j++) cnt += (u[q][j] < C) ? 1 : 0;
        #pragma unroll
        for (int off = 32; off >= 1; off >>= 1) cnt += __shfl_xor(cnt, off, 64);
        if (lane == 0) partial[wid] = cnt;
        __syncthreads();
        int tot = partial[0] + partial[1] + partial[2] + partial[3];
        __syncthreads();
        if (tot <= 128) P = C;
    }
    return P;
}

__global__ __launch_bounds__(256) void sel_h34(
    const float* __restrict__ bias, float* out)
{
    int bx = blockIdx.x;
    int n = bx / NPOS;
    int p = bx % NPOS;
    int t = threadIdx.x;
    int lane = t & 63, wid = t >> 6;
    __shared__ int partial[4];

    unsigned u3[4][8], u4[4][8];
    long nb = (long)n * 8192 * NPOS;
    #pragma unroll
    for (int j = 0; j < 8; j++) {
        int f = t + 256 * j;
        float c3  = out[nb + (long)(f       ) * NPOS + p];
        float cf3 = out[nb + (long)(f + 2048) * NPOS + p];
        float c4  = out[nb + (long)(f + 4096) * NPOS + p];
        float cf4 = out[nb + (long)(f + 6144) * NPOS + p];
        float b   = bias[f];
        u3[0][j] = map32(__fsub_rn(b, c3));
        u3[1][j] = map32(__fsub_rn(b, cf3));
        u3[2][j] = map32(__fadd_rn(c3, b));
        u3[3][j] = map32(__fadd_rn(cf3, b));
        u4[0][j] = map32(__fsub_rn(b, c4));
        u4[1][j] = map32(__fsub_rn(b, cf4));
        u4[2][j] = map32(__fadd_rn(c4, b));
        u4[3][j] = map32(__fadd_rn(cf4, b));
    }
    unsigned P3 = bisect128(u3, lane, wid, partial);
    unsigned P4 = bisect128(u4, lane, wid, partial);
    #pragma unroll
    for (int j = 0; j < 8; j++) {
        int f = t + 256 * j;
        #pragma unroll
        for (int q = 0; q < 4; q++) {
            int s = (u3[q][j] < P3) && (u4[q][j] < P4);
            out[nb + (long)(q * 2048 + f) * NPOS + p] = s ? 1.0f : 0.0f;
        }
    }
}

extern "C" void kernel_launch(void* const* d_in, const int* in_sizes, int n_in,
                              void* d_out, int out_size, void* d_ws, size_t ws_size,
                              hipStream_t stream)
{
    const float* img  = (const float*)d_in[0];
    const float* wgt  = (const float*)d_in[1];
    const float* bias = (const float*)d_in[2];
    float* out = (float*)d_out;

    size_t convB = (size_t)16 * 2048 * NPOS * sizeof(float4);  // 382,205,952
    size_t thrB  = (size_t)2 * NTHR * sizeof(unsigned);        //      93,312
    size_t strB  = (size_t)2048 * 108 * sizeof(float);         //     884,736
    size_t need  = convB + thrB + 4 * strB;                    // 385,838,208

    if (ws_size >= need) {
        float4*   B   = (float4*)d_ws;
        unsigned* thr = (unsigned*)((char*)d_ws + convB);
        float* s3f = (float*)((char*)d_ws + convB + thrB);
        float* s3r = s3f + 2048 * 108;
        float* s4f = s3r + 2048 * 108;
        float* s4r = s4f + 2048 * 108;
        prep_weights<<<2048, 128, 0, stream>>>(wgt, s3f, s3r, s4f, s4r);
        conv_pos<<<64 * 3 * 16, 256, 0, stream>>>(img, s3f, s3r, s4f, s4r, B);
        thresh_kernel<<<NTHR, 256, 0, stream>>>(B, bias, thr);
        writeout<<<16 * 32 * 3, 256, 0, stream>>>(B, bias, thr, out);
    } else {
        conv_h34<<<16 * 27 * 32, 256, 0, stream>>>(img, wgt, out);
        sel_h34<<<NTHR, 256, 0, stream>>>(bias, out);
    }
}